// Round 1
// baseline (150.851 us; speedup 1.0000x reference)
//
#include <hip/hip_runtime.h>

// Problem: KL( N(pm, ps^2) || N(qm, qs^2) ) elementwise over [32,128,32,64],
// sum over (N,D), mean over (B,L)  ==  sum_all(kl_elem) / (B*L).
// kl_elem = 0.5*(r^2 + d^2 - 1) - log(r),  r = ps/qs, d = (qm-pm)/qs.

constexpr int TOTAL  = 32 * 128 * 32 * 64;   // 8388608 elements
constexpr int N4     = TOTAL / 4;            // float4 count per input
constexpr int BLOCK  = 256;
constexpr int GRID   = 2048;                 // 8 blocks/CU on 256 CUs
constexpr float INV_BL = 1.0f / (32.0f * 128.0f);

__global__ __launch_bounds__(BLOCK) void kl_partial_kernel(
    const float4* __restrict__ pm, const float4* __restrict__ ps,
    const float4* __restrict__ qm, const float4* __restrict__ qs,
    float* __restrict__ partial)
{
    const int tid    = blockIdx.x * BLOCK + threadIdx.x;
    const int stride = GRID * BLOCK;

    float acc = 0.0f;
    for (int i = tid; i < N4; i += stride) {
        float4 a = pm[i];   // prior_mu
        float4 b = ps[i];   // prior_sigma
        float4 c = qm[i];   // post_mu
        float4 d = qs[i];   // post_sigma

        {
            float inv = 1.0f / d.x;
            float r   = b.x * inv;
            float df  = (c.x - a.x) * inv;
            acc += 0.5f * (r * r + df * df - 1.0f) - __logf(r);
        }
        {
            float inv = 1.0f / d.y;
            float r   = b.y * inv;
            float df  = (c.y - a.y) * inv;
            acc += 0.5f * (r * r + df * df - 1.0f) - __logf(r);
        }
        {
            float inv = 1.0f / d.z;
            float r   = b.z * inv;
            float df  = (c.z - a.z) * inv;
            acc += 0.5f * (r * r + df * df - 1.0f) - __logf(r);
        }
        {
            float inv = 1.0f / d.w;
            float r   = b.w * inv;
            float df  = (c.w - a.w) * inv;
            acc += 0.5f * (r * r + df * df - 1.0f) - __logf(r);
        }
    }

    // wave-64 reduction
    #pragma unroll
    for (int off = 32; off > 0; off >>= 1)
        acc += __shfl_down(acc, off, 64);

    __shared__ float smem[BLOCK / 64];
    const int lane = threadIdx.x & 63;
    const int wid  = threadIdx.x >> 6;
    if (lane == 0) smem[wid] = acc;
    __syncthreads();

    if (threadIdx.x == 0) {
        float t = 0.0f;
        #pragma unroll
        for (int w = 0; w < BLOCK / 64; ++w) t += smem[w];
        partial[blockIdx.x] = t;
    }
}

__global__ __launch_bounds__(BLOCK) void kl_final_kernel(
    const float* __restrict__ partial, float* __restrict__ out)
{
    float acc = 0.0f;
    for (int i = threadIdx.x; i < GRID; i += BLOCK)
        acc += partial[i];

    #pragma unroll
    for (int off = 32; off > 0; off >>= 1)
        acc += __shfl_down(acc, off, 64);

    __shared__ float smem[BLOCK / 64];
    const int lane = threadIdx.x & 63;
    const int wid  = threadIdx.x >> 6;
    if (lane == 0) smem[wid] = acc;
    __syncthreads();

    if (threadIdx.x == 0) {
        float t = 0.0f;
        #pragma unroll
        for (int w = 0; w < BLOCK / 64; ++w) t += smem[w];
        out[0] = t * INV_BL;
    }
}

extern "C" void kernel_launch(void* const* d_in, const int* in_sizes, int n_in,
                              void* d_out, int out_size, void* d_ws, size_t ws_size,
                              hipStream_t stream) {
    const float4* pm = (const float4*)d_in[0];  // prior_mu
    const float4* ps = (const float4*)d_in[1];  // prior_sigma
    const float4* qm = (const float4*)d_in[2];  // post_mu
    const float4* qs = (const float4*)d_in[3];  // post_sigma
    float* partial = (float*)d_ws;              // GRID floats = 8 KiB scratch
    float* out     = (float*)d_out;

    kl_partial_kernel<<<GRID, BLOCK, 0, stream>>>(pm, ps, qm, qs, partial);
    kl_final_kernel<<<1, BLOCK, 0, stream>>>(partial, out);
}